// Round 2
// baseline (1152.794 us; speedup 1.0000x reference)
//
#include <hip/hip_runtime.h>

typedef unsigned short u16;
typedef __attribute__((ext_vector_type(8))) short short8;
typedef __attribute__((ext_vector_type(4))) float f32x4;

#define DE 512   // embed / model dim
#define SL 2048  // sequence length
#define NB 4     // batch
#define NH 8     // heads
#define HD 64    // head dim

__device__ __forceinline__ float bf2f(u16 h) {
    union { unsigned u; float f; } v; v.u = ((unsigned)h) << 16; return v.f;
}
__device__ __forceinline__ u16 f2bf(float f) {
    union { float f; unsigned u; } v; v.f = f;
    unsigned u = v.u;
    return (u16)((u + 0x7FFFu + ((u >> 16) & 1u)) >> 16);  // RNE
}
// load 8 consecutive fp32, round to bf16 fragment
__device__ __forceinline__ short8 ld8f(const float* __restrict__ p) {
    const float4 a = *(const float4*)p;
    const float4 b = *(const float4*)(p + 4);
    short8 r;
    ((u16*)&r)[0] = f2bf(a.x); ((u16*)&r)[1] = f2bf(a.y);
    ((u16*)&r)[2] = f2bf(a.z); ((u16*)&r)[3] = f2bf(a.w);
    ((u16*)&r)[4] = f2bf(b.x); ((u16*)&r)[5] = f2bf(b.y);
    ((u16*)&r)[6] = f2bf(b.z); ((u16*)&r)[7] = f2bf(b.w);
    return r;
}

// out[t][c] = sum_i X[t][i] * W[c][i] + bias[c];  M=8192 tokens, N=K=512.
// XBF: X is bf16 (ws intermediate) else fp32. W/bias always fp32.
// MODE 0: fp32 out, plain [t][512]
// MODE 1: bf16 out, head-split [b][h][t][64]
// MODE 2: bf16 out, head-split transposed [b][h][d][t]  (for V)
template <bool XBF, int MODE>
__global__ __launch_bounds__(256) void gemm512(const void* __restrict__ Xv,
                                               const float* __restrict__ W,
                                               const float* __restrict__ bias,
                                               void* __restrict__ outv) {
    const int lane = threadIdx.x & 63;
    const int wave = threadIdx.x >> 6;       // 0..3
    const int q16 = lane & 15, quad = lane >> 4;
    const int row0 = blockIdx.x * 64 + wave * 16;  // token tile (16 rows per wave)
    const int col0 = blockIdx.y * 64;              // output-channel tile

    f32x4 acc[4] = {};
    #pragma unroll 4
    for (int kk = 0; kk < DE; kk += 32) {
        short8 a;
        if (XBF)
            a = *(const short8*)((const u16*)Xv + (size_t)(row0 + q16) * DE + kk + quad * 8);
        else
            a = ld8f((const float*)Xv + (size_t)(row0 + q16) * DE + kk + quad * 8);
        #pragma unroll
        for (int ct = 0; ct < 4; ++ct) {
            short8 bw = ld8f(W + (size_t)(col0 + ct * 16 + q16) * DE + kk + quad * 8);
            acc[ct] = __builtin_amdgcn_mfma_f32_16x16x32_bf16(a, bw, acc[ct], 0, 0, 0);
        }
    }

    #pragma unroll
    for (int ct = 0; ct < 4; ++ct) {
        const int col = col0 + ct * 16 + q16;        // C/D col = lane&15
        const float bv = bias[col];
        if (MODE == 2) {
            const int tg0 = row0 + quad * 4;         // 4 consecutive tokens (r=0..3)
            const int b = tg0 >> 11, t0 = tg0 & 2047;
            const int h = col >> 6, d = col & 63;
            ushort4 pk;
            pk.x = f2bf(acc[ct][0] + bv);
            pk.y = f2bf(acc[ct][1] + bv);
            pk.z = f2bf(acc[ct][2] + bv);
            pk.w = f2bf(acc[ct][3] + bv);
            *(ushort4*)((u16*)outv + ((size_t)((b * NH + h) * HD + d) << 11) + t0) = pk;
        } else if (MODE == 1) {
            const int h = col >> 6, d = col & 63;
            #pragma unroll
            for (int r = 0; r < 4; ++r) {
                const int tg = row0 + quad * 4 + r;  // C/D row = quad*4 + r
                const int b = tg >> 11, t = tg & 2047;
                ((u16*)outv)[(((size_t)(b * NH + h) * SL + t) << 6) + d] = f2bf(acc[ct][r] + bv);
            }
        } else {
            #pragma unroll
            for (int r = 0; r < 4; ++r) {
                const int tg = row0 + quad * 4 + r;
                ((float*)outv)[(size_t)tg * DE + col] = acc[ct][r] + bv;
            }
        }
    }
}

// One block: (b, h, 32 q-rows). S=QK^T/8, u=exp(s) (mask->0) into LDS (bf16),
// row sums, write normalized attn (fp32), then O = (P@V)/l (bf16 to ws).
__global__ __launch_bounds__(512) void attn_kernel(const u16* __restrict__ Q,
                                                   const u16* __restrict__ K,
                                                   const u16* __restrict__ Vt,
                                                   const int* __restrict__ mask,
                                                   float* __restrict__ attn_out,
                                                   u16* __restrict__ Obuf) {
    __shared__ __align__(16) u16 P[32][2056];   // +8 pad: PV A-frag reads 2-way only
    __shared__ float linv[32];

    const int tid = threadIdx.x;
    const int lane = tid & 63, wave = tid >> 6;  // 8 waves
    const int q16 = lane & 15, quad = lane >> 4;
    const int qblk = blockIdx.x, h = blockIdx.y, b = blockIdx.z;
    const int qtile = wave >> 2;   // 0/1 -> q rows [0..15]/[16..31]
    const int kq = wave & 3;       // k quarter: 512 cols each
    const int qbase = qblk * 32;

    const u16* qplane = Q + (size_t)((b * NH + h) * SL) * HD;
    const u16* kplane = K + (size_t)((b * NH + h) * SL) * HD;

    const u16* qrow = qplane + (qbase + qtile * 16 + q16) * HD + quad * 8;
    const short8 aq0 = *(const short8*)(qrow);
    const short8 aq1 = *(const short8*)(qrow + 32);

    // ---- Phase 1: S tiles -> u = exp(s/8) (masked -> 0) into LDS ----
    const int qg0 = qbase + qtile * 16 + quad * 4;  // q row (within b) for r=0
    for (int kt = 0; kt < 32; ++kt) {
        const int kbase = kq * 512 + kt * 16;
        const u16* krow = kplane + (kbase + q16) * HD + quad * 8;
        short8 b0 = *(const short8*)(krow);
        short8 b1 = *(const short8*)(krow + 32);
        f32x4 s = {};
        s = __builtin_amdgcn_mfma_f32_16x16x32_bf16(aq0, b0, s, 0, 0, 0);
        s = __builtin_amdgcn_mfma_f32_16x16x32_bf16(aq1, b1, s, 0, 0, 0);
        const int* mrow = mask + (size_t)(b * SL + qg0) * SL + kbase + q16;
        #pragma unroll
        for (int r = 0; r < 4; ++r) {
            const int mv = mrow[(size_t)r * SL];
            const float u = mv ? 0.0f : __expf(s[r] * 0.125f);
            P[qtile * 16 + quad * 4 + r][kbase + q16] = f2bf(u);
        }
    }
    __syncthreads();

    // ---- Phase 2: row sums (16 threads per row) ----
    const int r32 = tid >> 4, cseg = tid & 15;
    float sum = 0.f;
    #pragma unroll
    for (int i = 0; i < 16; ++i) {
        const int c = cseg * 8 + i * 128;
        short8 v = *(const short8*)&P[r32][c];
        #pragma unroll
        for (int j = 0; j < 8; ++j) sum += bf2f(((u16*)&v)[j]);
    }
    #pragma unroll
    for (int off = 1; off < 16; off <<= 1) sum += __shfl_xor(sum, off);
    const float inv = 1.0f / sum;
    if ((lane & 15) == 0) linv[r32] = inv;
    __syncthreads();

    // ---- Phase 3: write normalized attn, fp32 (coalesced 16B stores) ----
    {
        const size_t rowbase = ((size_t)((b * NH + h) * SL + qbase + r32)) * SL;
        #pragma unroll
        for (int i = 0; i < 16; ++i) {
            const int c = cseg * 8 + i * 128;
            short8 v = *(const short8*)&P[r32][c];
            float4 w0, w1;
            w0.x = bf2f(((u16*)&v)[0]) * inv;
            w0.y = bf2f(((u16*)&v)[1]) * inv;
            w0.z = bf2f(((u16*)&v)[2]) * inv;
            w0.w = bf2f(((u16*)&v)[3]) * inv;
            w1.x = bf2f(((u16*)&v)[4]) * inv;
            w1.y = bf2f(((u16*)&v)[5]) * inv;
            w1.z = bf2f(((u16*)&v)[6]) * inv;
            w1.w = bf2f(((u16*)&v)[7]) * inv;
            *(float4*)(attn_out + rowbase + c) = w0;
            *(float4*)(attn_out + rowbase + c + 4) = w1;
        }
    }

    // ---- Phase 4: O = P @ V  (Vt stored [d][t], so B-frag is contiguous) ----
    const int dt = wave & 3, qt = wave >> 2;   // one (q-tile, d-tile) per wave
    const u16* vplane = Vt + (size_t)((b * NH + h) * HD) * SL;
    f32x4 o = {};
    #pragma unroll 4
    for (int kk = 0; kk < SL; kk += 32) {
        short8 a = *(const short8*)&P[qt * 16 + q16][kk + quad * 8];
        short8 bv = *(const short8*)(vplane + (dt * 16 + q16) * SL + kk + quad * 8);
        o = __builtin_amdgcn_mfma_f32_16x16x32_bf16(a, bv, o, 0, 0, 0);
    }
    #pragma unroll
    for (int r = 0; r < 4; ++r) {
        const int qrow = qt * 16 + quad * 4 + r;
        const float val = o[r] * linv[qrow];
        const int qg = qbase + qrow;
        Obuf[(size_t)(b * SL + qg) * DE + h * HD + dt * 16 + q16] = f2bf(val);
    }
}

extern "C" void kernel_launch(void* const* d_in, const int* in_sizes, int n_in,
                              void* d_out, int out_size, void* d_ws, size_t ws_size,
                              hipStream_t stream) {
    const float* x_q = (const float*)d_in[0];
    const float* x_k = (const float*)d_in[1];
    const float* x_v = (const float*)d_in[2];
    const int* mask = (const int*)d_in[3];
    const float* Wq = (const float*)d_in[4];
    const float* bq = (const float*)d_in[5];
    const float* Wk = (const float*)d_in[6];
    const float* bk = (const float*)d_in[7];
    const float* Wv = (const float*)d_in[8];
    const float* bv = (const float*)d_in[9];
    const float* Wo = (const float*)d_in[10];
    const float* bo = (const float*)d_in[11];

    // ws layout: q | k | vt | o_cat, each B*H*L*HD = 4,194,304 bf16 (8 MiB) -> 32 MiB
    u16* ws = (u16*)d_ws;
    u16* qb = ws;
    u16* kb = ws + 4194304;
    u16* vt = ws + 2 * 4194304;
    u16* ob = ws + 3 * 4194304;

    float* outp = (float*)d_out;
    float* attn_out = outp + 4194304;  // final is B*L*DE = 4,194,304 elems

    dim3 gg(128, 8);
    gemm512<false, 1><<<gg, 256, 0, stream>>>(x_q, Wq, bq, qb);
    gemm512<false, 1><<<gg, 256, 0, stream>>>(x_k, Wk, bk, kb);
    gemm512<false, 2><<<gg, 256, 0, stream>>>(x_v, Wv, bv, vt);
    attn_kernel<<<dim3(64, 8, 4), 512, 0, stream>>>(qb, kb, vt, mask, attn_out, ob);
    gemm512<true, 0><<<gg, 256, 0, stream>>>(ob, Wo, bo, outp);
}